// Round 15
// baseline (229.592 us; speedup 1.0000x reference)
//
#include <hip/hip_runtime.h>

#define INF 3.4e38f

// v_med3_u32: middle of three uints (sorted-insert primitive)
__device__ __forceinline__ unsigned med3u(unsigned a, unsigned b, unsigned c) {
    unsigned d;
    asm("v_med3_u32 %0, %1, %2, %3" : "=v"(d) : "v"(a), "v"(b), "v"(c));
    return d;
}

// insert u into sorted top-5 key list (k0<=k1<=k2<=k3<=k4): 5 VALU ops
__device__ __forceinline__ void ins5(unsigned u, unsigned& k0, unsigned& k1,
                                     unsigned& k2, unsigned& k3, unsigned& k4)
{
    unsigned n1 = med3u(k0, k1, u);
    unsigned n2 = med3u(k1, k2, u);
    unsigned n3 = med3u(k2, k3, u);
    unsigned n4 = med3u(k3, k4, u);
    k0 = k0 < u ? k0 : u;
    k1 = n1; k2 = n2; k3 = n3; k4 = n4;
}

// exact (value,index) insert with index tiebreak (resolution only)
__device__ __forceinline__ void ins3t(float e, int ei,
                                      float& c0, float& c1, float& c2,
                                      int& i0, int& i1, int& i2)
{
    bool l0 = (e < c0) || (e == c0 && ei < i0);
    bool l1 = (e < c1) || (e == c1 && ei < i1);
    bool l2 = (e < c2) || (e == c2 && ei < i2);
    c2 = l1 ? c1 : (l2 ? e  : c2);
    i2 = l1 ? i1 : (l2 ? ei : i2);
    c1 = l0 ? c0 : (l1 ? e  : c1);
    i1 = l0 ? i0 : (l1 ? ei : i1);
    c0 = l0 ? e  : c0;
    i0 = l0 ? ei : i0;
}

// ---------------- Pack centroids + zero gstats ----------------
__global__ __launch_bounds__(256) void fp_pack(
    const float* __restrict__ cents, float4* __restrict__ cpk,
    float* __restrict__ gstats, int M)
{
    if (blockIdx.x == 0) gstats[threadIdx.x] = 0.0f;   // 256 floats
    int m = blockIdx.x * 256 + threadIdx.x;
    if (m < M) {
        float x = cents[3*m], y = cents[3*m+1], z = cents[3*m+2];
        cpk[m] = make_float4(x, y, z, 0.5f * fmaf(x, x, fmaf(y, y, z*z)));
    }
}

// ---------------- Kernel A: KNN + IDW interp + Linear1 -> hT ----------------
// Block = 512 thr / 8 waves / 64 vertices (lane = vertex). Wave w scans
// [Mw/8, M(w+1)/8) with wave-uniform cpk loads (SMEM path), 4-deep software
// pipeline (R13: 75->60.5us). Packed key = (bits of 0.5*d^2+1e-4, low 11
// bits = index). Wave 0 merges, exact-resolves top-3, publishes widx/wwt to
// LDS; gather (8 thr/vertex) + GEMM1 (wave w -> 16 cols, W1 stream
// distance-2 pipelined -- same scalar-stall fix) follow in-kernel.
__global__ __launch_bounds__(512, 8) void fp_main(
    const float* __restrict__ verts,
    const float* __restrict__ cents,
    const float4* __restrict__ cpk,
    const float* __restrict__ feats,
    const float* __restrict__ W1,
    const float* __restrict__ b1,
    float* __restrict__ hT,
    int N, int M)
{
    // aliased region: merge buf uint[8][5][64] (10KB) / interpL [64][65] (16.64KB)
    __shared__ __align__(16) float smem[4160];
    __shared__ int   widx[64][3];
    __shared__ float wwt [64][3];
    float*    interpL = smem;
    unsigned* mk      = (unsigned*)smem;

    int t = threadIdx.x, lane = t & 63;
    int w  = __builtin_amdgcn_readfirstlane(t >> 6);   // 0..7
    int cw = w << 4;                                    // 16-col GEMM slice

    int v0 = blockIdx.x * 64;
    int vtx = v0 + lane;
    int vs  = vtx < N ? vtx : N - 1;
    float vx = verts[3*vs], vy = verts[3*vs+1], vz = verts[3*vs+2];

    // bias: s' = 0.5*|c|^2 - v.c + h = 0.5*d^2 + 1e-4  (>0, uint-order monotone)
    float h = 0.5f * fmaf(vx, vx, fmaf(vy, vy, vz*vz)) + 1e-4f;

    unsigned k0 = 0xFFFFFFFFu, k1 = 0xFFFFFFFFu, k2 = 0xFFFFFFFFu,
             k3 = 0xFFFFFFFFu, k4 = 0xFFFFFFFFu;

#define PROC(c, midx)                                                          \
    {                                                                          \
        float sp = fmaf(-vx, (c).x, fmaf(-vy, (c).y,                           \
                        fmaf(-vz, (c).z, (c).w + h)));                         \
        unsigned u = (__float_as_uint(sp) & 0xFFFFF800u) | (unsigned)(midx);   \
        ins5(u, k0, k1, k2, k3, k4);                                           \
    }

    int mw0 = (M * w) >> 3, mw1 = (M * (w + 1)) >> 3;
    int m = mw0;
    int nPipe = (mw1 - mw0) & ~3;          // multiple of 4
    if (nPipe >= 8) {
        float4 p0 = cpk[m+0], p1 = cpk[m+1], p2 = cpk[m+2], p3 = cpk[m+3];
        for (; m + 8 <= mw0 + nPipe; m += 4) {
            float4 n0 = cpk[m+4], n1 = cpk[m+5], n2 = cpk[m+6], n3 = cpk[m+7];
            PROC(p0, m+0); PROC(p1, m+1); PROC(p2, m+2); PROC(p3, m+3);
            p0 = n0; p1 = n1; p2 = n2; p3 = n3;
        }
        PROC(p0, m+0); PROC(p1, m+1); PROC(p2, m+2); PROC(p3, m+3);
        m += 4;
    }
    for (; m < mw1; ++m) {                 // remainder (M not mult of 32)
        float4 c = cpk[m];
        PROC(c, m);
    }
#undef PROC

    // publish per-wave top-5 (stride-1 across lanes: conflict-free)
    mk[(w*5 + 0)*64 + lane] = k0;
    mk[(w*5 + 1)*64 + lane] = k1;
    mk[(w*5 + 2)*64 + lane] = k2;
    mk[(w*5 + 3)*64 + lane] = k3;
    mk[(w*5 + 4)*64 + lane] = k4;
    __syncthreads();

    if (w == 0) {
        // fold in waves 1..7 (keys globally unique via index bits)
        #pragma unroll
        for (int ww = 1; ww < 8; ++ww) {
            unsigned e0 = mk[(ww*5 + 0)*64 + lane];
            unsigned e1 = mk[(ww*5 + 1)*64 + lane];
            unsigned e2 = mk[(ww*5 + 2)*64 + lane];
            unsigned e3 = mk[(ww*5 + 3)*64 + lane];
            unsigned e4 = mk[(ww*5 + 4)*64 + lane];
            ins5(e0, k0, k1, k2, k3, k4);
            ins5(e1, k0, k1, k2, k3, k4);
            ins5(e2, k0, k1, k2, k3, k4);
            ins5(e3, k0, k1, k2, k3, k4);
            ins5(e4, k0, k1, k2, k3, k4);
        }
        // exact d^2 for the 5 candidates from global cents (24KB, cache-hot),
        // exact top-3-of-5 with index tiebreak resolves quantization ties.
        int J0 = (int)(k0 & 2047u), J1 = (int)(k1 & 2047u), J2 = (int)(k2 & 2047u),
            J3 = (int)(k3 & 2047u), J4 = (int)(k4 & 2047u);
        float c0 = INF, c1 = INF, c2 = INF;
        int   i0 = 0x7fffffff, i1 = 0x7fffffff, i2 = 0x7fffffff;
        #pragma unroll
        for (int q = 0; q < 5; ++q) {
            int j = (q == 0) ? J0 : (q == 1) ? J1 : (q == 2) ? J2 : (q == 3) ? J3 : J4;
            float ax = cents[3*j], ay = cents[3*j+1], az = cents[3*j+2];
            float dx = vx - ax, dy = vy - ay, dz = vz - az;
            float dd = fmaf(dx, dx, fmaf(dy, dy, dz*dz));
            ins3t(dd, j, c0, c1, c2, i0, i1, i2);
        }
        float d0 = c0, d1 = c1, d2 = c2;
        bool z0 = (d0 == 0.0f), z1 = (d1 == 0.0f), z2 = (d2 == 0.0f);
        float w0, w1, w2;
        if (z0 || z1 || z2) {
            w0 = z0 ? 1.0f : 0.0f;
            w1 = z1 ? 1.0f : 0.0f;
            w2 = z2 ? 1.0f : 0.0f;
        } else {
            w0 = 1.0f / d0; w1 = 1.0f / d1; w2 = 1.0f / d2;
        }
        float winv = 1.0f / (w0 + w1 + w2);
        widx[lane][0] = i0; wwt[lane][0] = w0 * winv;
        widx[lane][1] = i1; wwt[lane][1] = w1 * winv;
        widx[lane][2] = i2; wwt[lane][2] = w2 * winv;
    }
    __syncthreads();   // mk reads done; widx/wwt published

    // gather: 8 threads/vertex, 8 feats each (overwrites merge-buf region)
    {
        int vloc = t >> 3, p = t & 7;
        int a0 = widx[vloc][0], a1 = widx[vloc][1], a2 = widx[vloc][2];
        float u0 = wwt[vloc][0], u1 = wwt[vloc][1], u2 = wwt[vloc][2];
        int fh = p * 8;
        const float4* f0 = (const float4*)(feats + (size_t)a0 * 64 + fh);
        const float4* f1 = (const float4*)(feats + (size_t)a1 * 64 + fh);
        const float4* f2 = (const float4*)(feats + (size_t)a2 * 64 + fh);
        float* dst = interpL + vloc * 65 + fh;
        #pragma unroll
        for (int q = 0; q < 2; ++q) {
            float4 A = f0[q], B = f1[q], C = f2[q];
            dst[4*q+0] = fmaf(u0, A.x, fmaf(u1, B.x, u2*C.x));
            dst[4*q+1] = fmaf(u0, A.y, fmaf(u1, B.y, u2*C.y));
            dst[4*q+2] = fmaf(u0, A.z, fmaf(u1, B.z, u2*C.z));
            dst[4*q+3] = fmaf(u0, A.w, fmaf(u1, B.w, u2*C.w));
        }
    }
    __syncthreads();

    // GEMM1: wave w -> cols [16w, 16w+16), lane -> vertex.
    // W1 row stream (wave-uniform SMEM) distance-2 pipelined: 3 rows x 16
    // floats live (~48 data SGPRs) so s_loads stay ahead of the fma chain.
    float acc[16];
    #pragma unroll
    for (int j = 0; j < 16; ++j) acc[j] = b1[cw + j];
    {
        const float* wbase = W1 + cw;
        float4 pA = *(const float4*)(wbase + 0);
        float4 pB = *(const float4*)(wbase + 4);
        float4 pC = *(const float4*)(wbase + 8);
        float4 pD = *(const float4*)(wbase + 12);
        float4 qA = *(const float4*)(wbase + 128 + 0);
        float4 qB = *(const float4*)(wbase + 128 + 4);
        float4 qC = *(const float4*)(wbase + 128 + 8);
        float4 qD = *(const float4*)(wbase + 128 + 12);
        #pragma unroll 4
        for (int d = 0; d < 64; ++d) {
            int dn = d + 2 < 64 ? d + 2 : 63;
            const float* wn = wbase + dn * 128;
            float4 nA = *(const float4*)(wn + 0);
            float4 nB = *(const float4*)(wn + 4);
            float4 nC = *(const float4*)(wn + 8);
            float4 nD = *(const float4*)(wn + 12);
            float x = interpL[lane * 65 + d];
            acc[ 0] = fmaf(x, pA.x, acc[ 0]);
            acc[ 1] = fmaf(x, pA.y, acc[ 1]);
            acc[ 2] = fmaf(x, pA.z, acc[ 2]);
            acc[ 3] = fmaf(x, pA.w, acc[ 3]);
            acc[ 4] = fmaf(x, pB.x, acc[ 4]);
            acc[ 5] = fmaf(x, pB.y, acc[ 5]);
            acc[ 6] = fmaf(x, pB.z, acc[ 6]);
            acc[ 7] = fmaf(x, pB.w, acc[ 7]);
            acc[ 8] = fmaf(x, pC.x, acc[ 8]);
            acc[ 9] = fmaf(x, pC.y, acc[ 9]);
            acc[10] = fmaf(x, pC.z, acc[10]);
            acc[11] = fmaf(x, pC.w, acc[11]);
            acc[12] = fmaf(x, pD.x, acc[12]);
            acc[13] = fmaf(x, pD.y, acc[13]);
            acc[14] = fmaf(x, pD.z, acc[14]);
            acc[15] = fmaf(x, pD.w, acc[15]);
            pA = qA; pB = qB; pC = qC; pD = qD;
            qA = nA; qB = nB; qC = nC; qD = nD;
        }
    }
    int gv = v0 + lane;
    if (gv < N) {
        #pragma unroll
        for (int j = 0; j < 16; ++j)
            hT[(size_t)(cw + j) * N + gv] = acc[j];   // coalesced across lanes
    }
}

// ---------------- Reduce: BN stats straight from hT (L3-resident) ----------------
// 512 blocks: channel = bid & 127, segment = bid >> 7 (4 segs/channel).
__global__ __launch_bounds__(256) void fp_reduce(
    const float* __restrict__ hT,
    float* __restrict__ gstats, int N)
{
    __shared__ float red[8];
    int ch  = blockIdx.x & 127;
    int seg = blockIdx.x >> 7;
    const float* row = hT + (size_t)ch * N;
    float s = 0.0f, s2 = 0.0f;

    if ((N & 3) == 0) {
        int n4  = N >> 2;
        int len = (n4 + 3) >> 2;
        int a = seg * len, b = a + len; if (b > n4) b = n4;
        const float4* r4 = (const float4*)row;
        for (int i = a + threadIdx.x; i < b; i += 256) {
            float4 v = r4[i];
            s  += (v.x + v.y) + (v.z + v.w);
            s2 += fmaf(v.x, v.x, fmaf(v.y, v.y, fmaf(v.z, v.z, v.w * v.w)));
        }
    } else {
        int len = (N + 3) >> 2;
        int a = seg * len, b = a + len; if (b > N) b = N;
        for (int i = a + threadIdx.x; i < b; i += 256) {
            float v = row[i]; s += v; s2 = fmaf(v, v, s2);
        }
    }

    #pragma unroll
    for (int o = 32; o; o >>= 1) {
        s  += __shfl_xor(s, o);
        s2 += __shfl_xor(s2, o);
    }
    int w = threadIdx.x >> 6;
    if ((threadIdx.x & 63) == 0) { red[w] = s; red[4 + w] = s2; }
    __syncthreads();
    if (threadIdx.x == 0) {
        atomicAdd(&gstats[ch],       (red[0] + red[1]) + (red[2] + red[3]));
        atomicAdd(&gstats[128 + ch], (red[4] + red[5]) + (red[6] + red[7]));
    }
}

// ---------------- Kernel C: BN + ReLU + Linear2 (LDS-staged, W2 pipelined) ----------------
// 512 thr / 8 waves x 16 cols. W2 row stream (wave-uniform SMEM, 8KB/wave
// slice x 8 waves = 64KB working set >> 16KB sK$ -> L2-latency misses)
// distance-2 pipelined: 3 rows x 16 floats live (~48 data SGPRs).
__global__ __launch_bounds__(512, 8) void fp_bn_mlp2(
    const float* __restrict__ hT,
    const float* __restrict__ gstats,
    const float* __restrict__ gamma,
    const float* __restrict__ beta,
    const float* __restrict__ W2,
    const float* __restrict__ b2,
    float* __restrict__ out,
    int N)
{
    __shared__ float scS[128], shS[128];
    __shared__ __align__(16) float hl[128 * 68];   // stage [128][68]; reuse [64][129]
    int t = threadIdx.x;
    if (t < 128) {
        float inv = 1.0f / (float)N;
        float mu  = gstats[t] * inv;
        float var = fmaf(-mu, mu, gstats[128 + t] * inv);
        var = fmaxf(var, 0.0f);
        float is = rsqrtf(var + 1e-5f);
        float sc = gamma[t] * is;
        scS[t] = sc;
        shS[t] = beta[t] - mu * sc;
    }
    __syncthreads();

    int r0 = blockIdx.x * 64;
    int N4 = N >> 2, r04 = r0 >> 2;
    const float4* hT4 = (const float4*)hT;

    // stage [128 ch][64 rows] with BN+ReLU applied: 2048 float4 / 512 thr
    #pragma unroll
    for (int jj = 0; jj < 4; ++jj) {
        int i4 = t + jj * 512;
        int k = i4 >> 4, r4 = i4 & 15;
        float4 v = make_float4(0.f, 0.f, 0.f, 0.f);
        if (r0 + 4*r4 < N) v = hT4[(size_t)k * N4 + r04 + r4];
        float sc = scS[k], sh = shS[k];
        float4 o;
        o.x = fmaxf(fmaf(v.x, sc, sh), 0.f);
        o.y = fmaxf(fmaf(v.y, sc, sh), 0.f);
        o.z = fmaxf(fmaf(v.z, sc, sh), 0.f);
        o.w = fmaxf(fmaf(v.w, sc, sh), 0.f);
        ((float4*)hl)[k * 17 + r4] = o;
    }
    __syncthreads();

    int lane = t & 63;
    int w  = __builtin_amdgcn_readfirstlane(t >> 6);
    int cw = w << 4;

    float acc[16];
    #pragma unroll
    for (int j = 0; j < 16; ++j) acc[j] = b2[cw + j];
    {
        const float* wbase = W2 + cw;
        float4 pA = *(const float4*)(wbase + 0);
        float4 pB = *(const float4*)(wbase + 4);
        float4 pC = *(const float4*)(wbase + 8);
        float4 pD = *(const float4*)(wbase + 12);
        float4 qA = *(const float4*)(wbase + 128 + 0);
        float4 qB = *(const float4*)(wbase + 128 + 4);
        float4 qC = *(const float4*)(wbase + 128 + 8);
        float4 qD = *(const float4*)(wbase + 128 + 12);
        #pragma unroll 4
        for (int k = 0; k < 128; ++k) {
            int kn = k + 2 < 128 ? k + 2 : 127;
            const float* wn = wbase + kn * 128;
            float4 nA = *(const float4*)(wn + 0);
            float4 nB = *(const float4*)(wn + 4);
            float4 nC = *(const float4*)(wn + 8);
            float4 nD = *(const float4*)(wn + 12);
            float x = hl[k * 68 + lane];           // stride-1 across lanes
            acc[ 0] = fmaf(x, pA.x, acc[ 0]);
            acc[ 1] = fmaf(x, pA.y, acc[ 1]);
            acc[ 2] = fmaf(x, pA.z, acc[ 2]);
            acc[ 3] = fmaf(x, pA.w, acc[ 3]);
            acc[ 4] = fmaf(x, pB.x, acc[ 4]);
            acc[ 5] = fmaf(x, pB.y, acc[ 5]);
            acc[ 6] = fmaf(x, pB.z, acc[ 6]);
            acc[ 7] = fmaf(x, pB.w, acc[ 7]);
            acc[ 8] = fmaf(x, pC.x, acc[ 8]);
            acc[ 9] = fmaf(x, pC.y, acc[ 9]);
            acc[10] = fmaf(x, pC.z, acc[10]);
            acc[11] = fmaf(x, pC.w, acc[11]);
            acc[12] = fmaf(x, pD.x, acc[12]);
            acc[13] = fmaf(x, pD.y, acc[13]);
            acc[14] = fmaf(x, pD.z, acc[14]);
            acc[15] = fmaf(x, pD.w, acc[15]);
            pA = qA; pB = qB; pC = qC; pD = qD;
            qA = nA; qB = nB; qC = nC; qD = nD;
        }
    }
    __syncthreads();   // done reading staged hl

    // transpose via LDS (reuse hl as [64][129]) for coalesced float4 stores
    #pragma unroll
    for (int j = 0; j < 16; ++j) hl[lane * 129 + cw + j] = acc[j];
    __syncthreads();

    #pragma unroll
    for (int jj = 0; jj < 4; ++jj) {
        int i4 = t + jj * 512;
        int r = i4 >> 5, cq = (i4 & 31) << 2;
        int row = r0 + r;
        if (row < N) {
            float4 o4 = make_float4(hl[r*129 + cq],     hl[r*129 + cq + 1],
                                    hl[r*129 + cq + 2], hl[r*129 + cq + 3]);
            *(float4*)(out + (size_t)row * 128 + cq) = o4;
        }
    }
}

extern "C" void kernel_launch(void* const* d_in, const int* in_sizes, int n_in,
                              void* d_out, int out_size, void* d_ws, size_t ws_size,
                              hipStream_t stream)
{
    (void)n_in; (void)out_size; (void)ws_size;
    const float* verts = (const float*)d_in[0];
    const float* cents = (const float*)d_in[1];
    const float* feats = (const float*)d_in[2];
    const float* W1    = (const float*)d_in[3];
    const float* b1    = (const float*)d_in[4];
    const float* gamma = (const float*)d_in[5];
    const float* beta  = (const float*)d_in[6];
    const float* W2    = (const float*)d_in[7];
    const float* b2    = (const float*)d_in[8];
    float* out = (float*)d_out;

    int N = in_sizes[0] / 3;
    int M = in_sizes[1] / 3;

    float*  gstats = (float*)d_ws;                       // 256 floats
    float*  hT     = (float*)((char*)d_ws + 1024);       // [128, N]
    float4* cpk    = (float4*)(hT + (size_t)128 * N);    // [M] packed centroids

    hipLaunchKernelGGL(fp_pack, dim3((M + 255) / 256), dim3(256), 0, stream,
                       cents, cpk, gstats, M);

    int nblk = (N + 63) / 64;
    hipLaunchKernelGGL(fp_main, dim3(nblk), dim3(512), 0, stream,
                       verts, cents, cpk, feats, W1, b1, hT, N, M);

    hipLaunchKernelGGL(fp_reduce, dim3(512), dim3(256), 0, stream,
                       hT, gstats, N);

    hipLaunchKernelGGL(fp_bn_mlp2, dim3(nblk), dim3(512), 0, stream,
                       hT, gstats, gamma, beta, W2, b2, out, N);
}

// Round 16
// 212.945 us; speedup vs baseline: 1.0782x; 1.0782x over previous
//
#include <hip/hip_runtime.h>

#define INF 3.4e38f

// v_med3_u32: middle of three uints (sorted-insert primitive)
__device__ __forceinline__ unsigned med3u(unsigned a, unsigned b, unsigned c) {
    unsigned d;
    asm("v_med3_u32 %0, %1, %2, %3" : "=v"(d) : "v"(a), "v"(b), "v"(c));
    return d;
}

// insert u into sorted top-5 key list (k0<=k1<=k2<=k3<=k4): 5 VALU ops
__device__ __forceinline__ void ins5(unsigned u, unsigned& k0, unsigned& k1,
                                     unsigned& k2, unsigned& k3, unsigned& k4)
{
    unsigned n1 = med3u(k0, k1, u);
    unsigned n2 = med3u(k1, k2, u);
    unsigned n3 = med3u(k2, k3, u);
    unsigned n4 = med3u(k3, k4, u);
    k0 = k0 < u ? k0 : u;
    k1 = n1; k2 = n2; k3 = n3; k4 = n4;
}

// exact (value,index) insert with index tiebreak (resolution only)
__device__ __forceinline__ void ins3t(float e, int ei,
                                      float& c0, float& c1, float& c2,
                                      int& i0, int& i1, int& i2)
{
    bool l0 = (e < c0) || (e == c0 && ei < i0);
    bool l1 = (e < c1) || (e == c1 && ei < i1);
    bool l2 = (e < c2) || (e == c2 && ei < i2);
    c2 = l1 ? c1 : (l2 ? e  : c2);
    i2 = l1 ? i1 : (l2 ? ei : i2);
    c1 = l0 ? c0 : (l1 ? e  : c1);
    i1 = l0 ? i0 : (l1 ? ei : i1);
    c0 = l0 ? e  : c0;
    i0 = l0 ? ei : i0;
}

// ---------------- Pack centroids + zero gstats ----------------
__global__ __launch_bounds__(256) void fp_pack(
    const float* __restrict__ cents, float4* __restrict__ cpk,
    float* __restrict__ gstats, int M)
{
    if (blockIdx.x == 0) gstats[threadIdx.x] = 0.0f;   // 256 floats
    int m = blockIdx.x * 256 + threadIdx.x;
    if (m < M) {
        float x = cents[3*m], y = cents[3*m+1], z = cents[3*m+2];
        cpk[m] = make_float4(x, y, z, 0.5f * fmaf(x, x, fmaf(y, y, z*z)));
    }
}

// ---------------- Kernel A: KNN + IDW interp + Linear1 -> hT ----------------
// Block = 512 thr / 8 waves / 64 vertices (lane = vertex). Wave w scans
// [Mw/8, M(w+1)/8) with wave-uniform cpk loads (SMEM path). 2-groups-ahead
// software pipeline: 12 float4 live (48 data SGPRs), 8 s_loads outstanding
// during each 4-group's ins5 chain (~160cy coverage vs ~200cy sK$ miss;
// R13's 1-ahead = 75->60.5us). Packed key = (bits of 0.5*d^2+1e-4, low 11
// bits = index). Wave 0 merges, exact-resolves top-3, publishes widx/wwt to
// LDS; gather (8 thr/vertex) + GEMM1 (simple compiler-scheduled loop --
// R15's manual GEMM pipeline regressed, reverted) follow in-kernel.
__global__ __launch_bounds__(512, 8) void fp_main(
    const float* __restrict__ verts,
    const float* __restrict__ cents,
    const float4* __restrict__ cpk,
    const float* __restrict__ feats,
    const float* __restrict__ W1,
    const float* __restrict__ b1,
    float* __restrict__ hT,
    int N, int M)
{
    // aliased region: merge buf uint[8][5][64] (10KB) / interpL [64][65] (16.64KB)
    __shared__ __align__(16) float smem[4160];
    __shared__ int   widx[64][3];
    __shared__ float wwt [64][3];
    float*    interpL = smem;
    unsigned* mk      = (unsigned*)smem;

    int t = threadIdx.x, lane = t & 63;
    int w  = __builtin_amdgcn_readfirstlane(t >> 6);   // 0..7
    int cw = w << 4;                                    // 16-col GEMM slice

    int v0 = blockIdx.x * 64;
    int vtx = v0 + lane;
    int vs  = vtx < N ? vtx : N - 1;
    float vx = verts[3*vs], vy = verts[3*vs+1], vz = verts[3*vs+2];

    // bias: s' = 0.5*|c|^2 - v.c + h = 0.5*d^2 + 1e-4  (>0, uint-order monotone)
    float h = 0.5f * fmaf(vx, vx, fmaf(vy, vy, vz*vz)) + 1e-4f;

    unsigned k0 = 0xFFFFFFFFu, k1 = 0xFFFFFFFFu, k2 = 0xFFFFFFFFu,
             k3 = 0xFFFFFFFFu, k4 = 0xFFFFFFFFu;

#define PROC(c, midx)                                                          \
    {                                                                          \
        float sp = fmaf(-vx, (c).x, fmaf(-vy, (c).y,                           \
                        fmaf(-vz, (c).z, (c).w + h)));                         \
        unsigned u = (__float_as_uint(sp) & 0xFFFFF800u) | (unsigned)(midx);   \
        ins5(u, k0, k1, k2, k3, k4);                                           \
    }

    int mw0 = (M * w) >> 3, mw1 = (M * (w + 1)) >> 3;
    int m = mw0, len = mw1 - mw0;
    if (len >= 12) {
        float4 p0 = cpk[m+0], p1 = cpk[m+1], p2 = cpk[m+2], p3 = cpk[m+3];
        float4 q0 = cpk[m+4], q1 = cpk[m+5], q2 = cpk[m+6], q3 = cpk[m+7];
        int mEnd = mw0 + ((len - 8) & ~3);
        #pragma unroll 3
        for (; m < mEnd; m += 4) {
            float4 n0 = cpk[m+ 8], n1 = cpk[m+ 9],
                   n2 = cpk[m+10], n3 = cpk[m+11];
            PROC(p0, m+0); PROC(p1, m+1); PROC(p2, m+2); PROC(p3, m+3);
            p0 = q0; p1 = q1; p2 = q2; p3 = q3;
            q0 = n0; q1 = n1; q2 = n2; q3 = n3;
        }
        PROC(p0, m+0); PROC(p1, m+1); PROC(p2, m+2); PROC(p3, m+3);
        m += 4;
        PROC(q0, m+0); PROC(q1, m+1); PROC(q2, m+2); PROC(q3, m+3);
        m += 4;
    }
    for (; m < mw1; ++m) {                 // remainder
        float4 c = cpk[m];
        PROC(c, m);
    }
#undef PROC

    // publish per-wave top-5 (stride-1 across lanes: conflict-free)
    mk[(w*5 + 0)*64 + lane] = k0;
    mk[(w*5 + 1)*64 + lane] = k1;
    mk[(w*5 + 2)*64 + lane] = k2;
    mk[(w*5 + 3)*64 + lane] = k3;
    mk[(w*5 + 4)*64 + lane] = k4;
    __syncthreads();

    if (w == 0) {
        // fold in waves 1..7 (keys globally unique via index bits)
        #pragma unroll
        for (int ww = 1; ww < 8; ++ww) {
            unsigned e0 = mk[(ww*5 + 0)*64 + lane];
            unsigned e1 = mk[(ww*5 + 1)*64 + lane];
            unsigned e2 = mk[(ww*5 + 2)*64 + lane];
            unsigned e3 = mk[(ww*5 + 3)*64 + lane];
            unsigned e4 = mk[(ww*5 + 4)*64 + lane];
            ins5(e0, k0, k1, k2, k3, k4);
            ins5(e1, k0, k1, k2, k3, k4);
            ins5(e2, k0, k1, k2, k3, k4);
            ins5(e3, k0, k1, k2, k3, k4);
            ins5(e4, k0, k1, k2, k3, k4);
        }
        // exact d^2 for the 5 candidates from global cents (24KB, cache-hot),
        // exact top-3-of-5 with index tiebreak resolves quantization ties.
        int J0 = (int)(k0 & 2047u), J1 = (int)(k1 & 2047u), J2 = (int)(k2 & 2047u),
            J3 = (int)(k3 & 2047u), J4 = (int)(k4 & 2047u);
        float c0 = INF, c1 = INF, c2 = INF;
        int   i0 = 0x7fffffff, i1 = 0x7fffffff, i2 = 0x7fffffff;
        #pragma unroll
        for (int q = 0; q < 5; ++q) {
            int j = (q == 0) ? J0 : (q == 1) ? J1 : (q == 2) ? J2 : (q == 3) ? J3 : J4;
            float ax = cents[3*j], ay = cents[3*j+1], az = cents[3*j+2];
            float dx = vx - ax, dy = vy - ay, dz = vz - az;
            float dd = fmaf(dx, dx, fmaf(dy, dy, dz*dz));
            ins3t(dd, j, c0, c1, c2, i0, i1, i2);
        }
        float d0 = c0, d1 = c1, d2 = c2;
        bool z0 = (d0 == 0.0f), z1 = (d1 == 0.0f), z2 = (d2 == 0.0f);
        float w0, w1, w2;
        if (z0 || z1 || z2) {
            w0 = z0 ? 1.0f : 0.0f;
            w1 = z1 ? 1.0f : 0.0f;
            w2 = z2 ? 1.0f : 0.0f;
        } else {
            w0 = 1.0f / d0; w1 = 1.0f / d1; w2 = 1.0f / d2;
        }
        float winv = 1.0f / (w0 + w1 + w2);
        widx[lane][0] = i0; wwt[lane][0] = w0 * winv;
        widx[lane][1] = i1; wwt[lane][1] = w1 * winv;
        widx[lane][2] = i2; wwt[lane][2] = w2 * winv;
    }
    __syncthreads();   // mk reads done; widx/wwt published

    // gather: 8 threads/vertex, 8 feats each (overwrites merge-buf region)
    {
        int vloc = t >> 3, p = t & 7;
        int a0 = widx[vloc][0], a1 = widx[vloc][1], a2 = widx[vloc][2];
        float u0 = wwt[vloc][0], u1 = wwt[vloc][1], u2 = wwt[vloc][2];
        int fh = p * 8;
        const float4* f0 = (const float4*)(feats + (size_t)a0 * 64 + fh);
        const float4* f1 = (const float4*)(feats + (size_t)a1 * 64 + fh);
        const float4* f2 = (const float4*)(feats + (size_t)a2 * 64 + fh);
        float* dst = interpL + vloc * 65 + fh;
        #pragma unroll
        for (int q = 0; q < 2; ++q) {
            float4 A = f0[q], B = f1[q], C = f2[q];
            dst[4*q+0] = fmaf(u0, A.x, fmaf(u1, B.x, u2*C.x));
            dst[4*q+1] = fmaf(u0, A.y, fmaf(u1, B.y, u2*C.y));
            dst[4*q+2] = fmaf(u0, A.z, fmaf(u1, B.z, u2*C.z));
            dst[4*q+3] = fmaf(u0, A.w, fmaf(u1, B.w, u2*C.w));
        }
    }
    __syncthreads();

    // GEMM1: wave w -> cols [16w, 16w+16), lane -> vertex (compiler-scheduled)
    float acc[16];
    #pragma unroll
    for (int j = 0; j < 16; ++j) acc[j] = b1[cw + j];
    #pragma unroll 8
    for (int d = 0; d < 64; ++d) {
        float x = interpL[lane * 65 + d];
        const float* wr = W1 + d * 128 + cw;
        #pragma unroll
        for (int j = 0; j < 16; ++j) acc[j] = fmaf(x, wr[j], acc[j]);
    }
    int gv = v0 + lane;
    if (gv < N) {
        #pragma unroll
        for (int j = 0; j < 16; ++j)
            hT[(size_t)(cw + j) * N + gv] = acc[j];   // coalesced across lanes
    }
}

// ---------------- Reduce: BN stats straight from hT (L3-resident) ----------------
// 512 blocks: channel = bid & 127, segment = bid >> 7 (4 segs/channel).
__global__ __launch_bounds__(256) void fp_reduce(
    const float* __restrict__ hT,
    float* __restrict__ gstats, int N)
{
    __shared__ float red[8];
    int ch  = blockIdx.x & 127;
    int seg = blockIdx.x >> 7;
    const float* row = hT + (size_t)ch * N;
    float s = 0.0f, s2 = 0.0f;

    if ((N & 3) == 0) {
        int n4  = N >> 2;
        int len = (n4 + 3) >> 2;
        int a = seg * len, b = a + len; if (b > n4) b = n4;
        const float4* r4 = (const float4*)row;
        for (int i = a + threadIdx.x; i < b; i += 256) {
            float4 v = r4[i];
            s  += (v.x + v.y) + (v.z + v.w);
            s2 += fmaf(v.x, v.x, fmaf(v.y, v.y, fmaf(v.z, v.z, v.w * v.w)));
        }
    } else {
        int len = (N + 3) >> 2;
        int a = seg * len, b = a + len; if (b > N) b = N;
        for (int i = a + threadIdx.x; i < b; i += 256) {
            float v = row[i]; s += v; s2 = fmaf(v, v, s2);
        }
    }

    #pragma unroll
    for (int o = 32; o; o >>= 1) {
        s  += __shfl_xor(s, o);
        s2 += __shfl_xor(s2, o);
    }
    int w = threadIdx.x >> 6;
    if ((threadIdx.x & 63) == 0) { red[w] = s; red[4 + w] = s2; }
    __syncthreads();
    if (threadIdx.x == 0) {
        atomicAdd(&gstats[ch],       (red[0] + red[1]) + (red[2] + red[3]));
        atomicAdd(&gstats[128 + ch], (red[4] + red[5]) + (red[6] + red[7]));
    }
}

// ---------------- Kernel C: BN + ReLU + Linear2 (LDS-staged, read-once) ----------------
// R8/R14 version (proven). 512 thr / 8 waves x 16 cols.
__global__ __launch_bounds__(512, 8) void fp_bn_mlp2(
    const float* __restrict__ hT,
    const float* __restrict__ gstats,
    const float* __restrict__ gamma,
    const float* __restrict__ beta,
    const float* __restrict__ W2,
    const float* __restrict__ b2,
    float* __restrict__ out,
    int N)
{
    __shared__ float scS[128], shS[128];
    __shared__ __align__(16) float hl[128 * 68];   // stage [128][68]; reuse [64][129]
    int t = threadIdx.x;
    if (t < 128) {
        float inv = 1.0f / (float)N;
        float mu  = gstats[t] * inv;
        float var = fmaf(-mu, mu, gstats[128 + t] * inv);
        var = fmaxf(var, 0.0f);
        float is = rsqrtf(var + 1e-5f);
        float sc = gamma[t] * is;
        scS[t] = sc;
        shS[t] = beta[t] - mu * sc;
    }
    __syncthreads();

    int r0 = blockIdx.x * 64;
    int N4 = N >> 2, r04 = r0 >> 2;
    const float4* hT4 = (const float4*)hT;

    // stage [128 ch][64 rows] with BN+ReLU applied: 2048 float4 / 512 thr
    #pragma unroll
    for (int jj = 0; jj < 4; ++jj) {
        int i4 = t + jj * 512;
        int k = i4 >> 4, r4 = i4 & 15;
        float4 v = make_float4(0.f, 0.f, 0.f, 0.f);
        if (r0 + 4*r4 < N) v = hT4[(size_t)k * N4 + r04 + r4];
        float sc = scS[k], sh = shS[k];
        float4 o;
        o.x = fmaxf(fmaf(v.x, sc, sh), 0.f);
        o.y = fmaxf(fmaf(v.y, sc, sh), 0.f);
        o.z = fmaxf(fmaf(v.z, sc, sh), 0.f);
        o.w = fmaxf(fmaf(v.w, sc, sh), 0.f);
        ((float4*)hl)[k * 17 + r4] = o;
    }
    __syncthreads();

    int lane = t & 63;
    int w  = __builtin_amdgcn_readfirstlane(t >> 6);
    int cw = w << 4;

    float acc[16];
    #pragma unroll
    for (int j = 0; j < 16; ++j) acc[j] = b2[cw + j];
    #pragma unroll 8
    for (int k = 0; k < 128; ++k) {
        float x = hl[k * 68 + lane];               // stride-1 across lanes
        const float* wr = W2 + k * 128 + cw;       // wave-uniform (SMEM) loads
        #pragma unroll
        for (int j = 0; j < 16; ++j) acc[j] = fmaf(x, wr[j], acc[j]);
    }
    __syncthreads();   // done reading staged hl

    // transpose via LDS (reuse hl as [64][129]) for coalesced float4 stores
    #pragma unroll
    for (int j = 0; j < 16; ++j) hl[lane * 129 + cw + j] = acc[j];
    __syncthreads();

    #pragma unroll
    for (int jj = 0; jj < 4; ++jj) {
        int i4 = t + jj * 512;
        int r = i4 >> 5, cq = (i4 & 31) << 2;
        int row = r0 + r;
        if (row < N) {
            float4 o4 = make_float4(hl[r*129 + cq],     hl[r*129 + cq + 1],
                                    hl[r*129 + cq + 2], hl[r*129 + cq + 3]);
            *(float4*)(out + (size_t)row * 128 + cq) = o4;
        }
    }
}

extern "C" void kernel_launch(void* const* d_in, const int* in_sizes, int n_in,
                              void* d_out, int out_size, void* d_ws, size_t ws_size,
                              hipStream_t stream)
{
    (void)n_in; (void)out_size; (void)ws_size;
    const float* verts = (const float*)d_in[0];
    const float* cents = (const float*)d_in[1];
    const float* feats = (const float*)d_in[2];
    const float* W1    = (const float*)d_in[3];
    const float* b1    = (const float*)d_in[4];
    const float* gamma = (const float*)d_in[5];
    const float* beta  = (const float*)d_in[6];
    const float* W2    = (const float*)d_in[7];
    const float* b2    = (const float*)d_in[8];
    float* out = (float*)d_out;

    int N = in_sizes[0] / 3;
    int M = in_sizes[1] / 3;

    float*  gstats = (float*)d_ws;                       // 256 floats
    float*  hT     = (float*)((char*)d_ws + 1024);       // [128, N]
    float4* cpk    = (float4*)(hT + (size_t)128 * N);    // [M] packed centroids

    hipLaunchKernelGGL(fp_pack, dim3((M + 255) / 256), dim3(256), 0, stream,
                       cents, cpk, gstats, M);

    int nblk = (N + 63) / 64;
    hipLaunchKernelGGL(fp_main, dim3(nblk), dim3(512), 0, stream,
                       verts, cents, cpk, feats, W1, b1, hT, N, M);

    hipLaunchKernelGGL(fp_reduce, dim3(512), dim3(256), 0, stream,
                       hT, gstats, N);

    hipLaunchKernelGGL(fp_bn_mlp2, dim3(nblk), dim3(512), 0, stream,
                       hT, gstats, gamma, beta, W2, b2, out, N);
}